// Round 1
// baseline (40.361 us; speedup 1.0000x reference)
//
#include <hip/hip_runtime.h>
#include <hip/hip_bf16.h>
#include <math.h>

// Problem constants (from reference): N=8 clouds, P=4096 points, D=3
constexpr int NB  = 8;
constexpr int PP  = 4096;

// Kernel A tiling
constexpr int TPB = 256;          // threads per block
constexpr int XPT = 4;            // x points per thread
constexpr int XCH = TPB * XPT;    // 1024 x points per block
constexpr int NXC = PP / XCH;     // 4 x chunks
constexpr int NYC = 8;            // y chunks
constexpr int YCH = PP / NYC;     // 512 y points per chunk

// ---------------------------------------------------------------------------
// Kernel A: for each (dir, cloud, x-chunk, y-chunk) compute per-x-point
// partial min squared distance over the y-chunk. Writes to ws:
//   ws[((dir*NB + n)*NYC + yc)*PP + xi] = a + min_j e_j   (INF if chunk empty)
// where a = |x|^2 and e_j = |y_j|^2 - 2 x.y_j  (3 FMA + 1 min per pair).
// ---------------------------------------------------------------------------
__global__ __launch_bounds__(TPB) void nn_partial(
    const float* __restrict__ x, const float* __restrict__ y,
    const int* __restrict__ xlen, const int* __restrict__ ylen,
    float* __restrict__ ws)
{
    __shared__ float4 sy[YCH];

    int bid = blockIdx.x;
    const int yc  = bid & (NYC - 1); bid >>= 3;   // NYC = 8
    const int xc  = bid & (NXC - 1); bid >>= 2;   // NXC = 4
    const int n   = bid & (NB - 1);  bid >>= 3;   // NB  = 8
    const int dir = bid;                           // 0: x->y, 1: y->x

    const float* __restrict__ xs = dir ? y : x;    // query set
    const float* __restrict__ ys = dir ? x : y;    // search set
    const int yl = (dir ? xlen : ylen)[n];         // valid points in search set

    // ---- stage y-chunk into LDS as (y0, y1, y2, |y|^2) ----
    const float* __restrict__ ybase = ys + ((size_t)n * PP + (size_t)yc * YCH) * 3;
    for (int p = (int)threadIdx.x; p < YCH; p += TPB) {
        float y0 = ybase[p * 3 + 0];
        float y1 = ybase[p * 3 + 1];
        float y2 = ybase[p * 3 + 2];
        sy[p] = make_float4(y0, y1, y2, fmaf(y0, y0, fmaf(y1, y1, y2 * y2)));
    }
    __syncthreads();

    int jend = yl - yc * YCH;
    if (jend > YCH) jend = YCH;           // may be <= 0 (empty chunk)

    // ---- load XPT x points, precompute -2x and |x|^2 ----
    float m0[XPT], m1[XPT], m2[XPT], a[XPT], emin[XPT];
    const int xi0 = xc * XCH + (int)threadIdx.x;
    const float* __restrict__ xb = xs + (size_t)n * PP * 3;
#pragma unroll
    for (int k = 0; k < XPT; ++k) {
        int xi = xi0 + k * TPB;
        float x0 = xb[xi * 3 + 0];
        float x1 = xb[xi * 3 + 1];
        float x2 = xb[xi * 3 + 2];
        m0[k] = -2.f * x0; m1[k] = -2.f * x1; m2[k] = -2.f * x2;
        a[k]  = fmaf(x0, x0, fmaf(x1, x1, x2 * x2));
        emin[k] = INFINITY;
    }

    // ---- main loop: 1 LDS b128 broadcast + 16 VALU ops per j ----
#pragma unroll 4
    for (int j = 0; j < jend; ++j) {
        float4 v = sy[j];
#pragma unroll
        for (int k = 0; k < XPT; ++k) {
            float e = fmaf(m0[k], v.x, fmaf(m1[k], v.y, fmaf(m2[k], v.z, v.w)));
            emin[k] = fminf(emin[k], e);
        }
    }

    float* __restrict__ w = ws + ((size_t)(dir * NB + n) * NYC + yc) * PP;
#pragma unroll
    for (int k = 0; k < XPT; ++k) {
        int xi = xi0 + k * TPB;
        w[xi] = a[k] + emin[k];
    }
}

// ---------------------------------------------------------------------------
// Kernel B: per (dir, cloud): min over y-chunks, mask padded x points,
// sum, divide by max(len,1)*NB. One block per (dir, n). Deterministic.
// ---------------------------------------------------------------------------
__global__ __launch_bounds__(256) void reduce_cloud(
    const float* __restrict__ ws,
    const int* __restrict__ xlen, const int* __restrict__ ylen,
    float* __restrict__ partial)
{
    const int b   = blockIdx.x;      // 0..15
    const int dir = b >> 3;
    const int n   = b & (NB - 1);
    const int xl  = (dir ? ylen : xlen)[n];   // valid query points

    const float* __restrict__ w = ws + (size_t)(dir * NB + n) * NYC * PP;
    float sum = 0.f;
    for (int i = (int)threadIdx.x; i < PP; i += 256) {
        float m = w[i];
#pragma unroll
        for (int c = 1; c < NYC; ++c) m = fminf(m, w[(size_t)c * PP + i]);
        if (i < xl) sum += m;
    }

    // block reduction (4 waves of 64)
#pragma unroll
    for (int off = 32; off > 0; off >>= 1) sum += __shfl_xor(sum, off);
    __shared__ float ls[4];
    const int lane = (int)threadIdx.x & 63;
    const int wv   = (int)threadIdx.x >> 6;
    if (lane == 0) ls[wv] = sum;
    __syncthreads();
    if (threadIdx.x == 0) {
        float tot = ls[0] + ls[1] + ls[2] + ls[3];
        int d = xl > 1 ? xl : 1;
        partial[b] = tot / (float)d / (float)NB;
    }
}

// ---------------------------------------------------------------------------
// Kernel C: sum the 16 per-(dir,cloud) partials -> scalar output.
// ---------------------------------------------------------------------------
__global__ __launch_bounds__(64) void final_sum(
    const float* __restrict__ partial, float* __restrict__ out)
{
    float v = ((int)threadIdx.x < 16) ? partial[threadIdx.x] : 0.f;
#pragma unroll
    for (int off = 32; off > 0; off >>= 1) v += __shfl_xor(v, off);
    if (threadIdx.x == 0) out[0] = v;
}

// ---------------------------------------------------------------------------
// Fallback (ws too small): no y-split; LDS multi-pass over y chunks; block
// sum + atomicAdd of the pre-divided contribution. Needs d_out zeroed first.
// ---------------------------------------------------------------------------
__global__ __launch_bounds__(TPB) void chamfer_atomic(
    const float* __restrict__ x, const float* __restrict__ y,
    const int* __restrict__ xlen, const int* __restrict__ ylen,
    float* __restrict__ out)
{
    __shared__ float4 sy[YCH];

    int bid = blockIdx.x;
    const int xc  = bid & (NXC - 1); bid >>= 2;
    const int n   = bid & (NB - 1);  bid >>= 3;
    const int dir = bid;

    const float* __restrict__ xs = dir ? y : x;
    const float* __restrict__ ys = dir ? x : y;
    const int yl = (dir ? xlen : ylen)[n];
    const int xl = (dir ? ylen : xlen)[n];

    float m0[XPT], m1[XPT], m2[XPT], a[XPT], emin[XPT];
    const int xi0 = xc * XCH + (int)threadIdx.x;
    const float* __restrict__ xb = xs + (size_t)n * PP * 3;
#pragma unroll
    for (int k = 0; k < XPT; ++k) {
        int xi = xi0 + k * TPB;
        float x0 = xb[xi * 3 + 0];
        float x1 = xb[xi * 3 + 1];
        float x2 = xb[xi * 3 + 2];
        m0[k] = -2.f * x0; m1[k] = -2.f * x1; m2[k] = -2.f * x2;
        a[k]  = fmaf(x0, x0, fmaf(x1, x1, x2 * x2));
        emin[k] = INFINITY;
    }

    for (int yc = 0; yc < NYC; ++yc) {
        const float* __restrict__ ybase = ys + ((size_t)n * PP + (size_t)yc * YCH) * 3;
        __syncthreads();
        for (int p = (int)threadIdx.x; p < YCH; p += TPB) {
            float y0 = ybase[p * 3 + 0];
            float y1 = ybase[p * 3 + 1];
            float y2 = ybase[p * 3 + 2];
            sy[p] = make_float4(y0, y1, y2, fmaf(y0, y0, fmaf(y1, y1, y2 * y2)));
        }
        __syncthreads();
        int jend = yl - yc * YCH;
        if (jend > YCH) jend = YCH;
#pragma unroll 4
        for (int j = 0; j < jend; ++j) {
            float4 v = sy[j];
#pragma unroll
            for (int k = 0; k < XPT; ++k) {
                float e = fmaf(m0[k], v.x, fmaf(m1[k], v.y, fmaf(m2[k], v.z, v.w)));
                emin[k] = fminf(emin[k], e);
            }
        }
    }

    float sum = 0.f;
#pragma unroll
    for (int k = 0; k < XPT; ++k) {
        int xi = xi0 + k * TPB;
        if (xi < xl) sum += a[k] + emin[k];
    }
#pragma unroll
    for (int off = 32; off > 0; off >>= 1) sum += __shfl_xor(sum, off);
    __shared__ float ls[4];
    const int lane = (int)threadIdx.x & 63;
    const int wv   = (int)threadIdx.x >> 6;
    if (lane == 0) ls[wv] = sum;
    __syncthreads();
    if (threadIdx.x == 0) {
        float tot = ls[0] + ls[1] + ls[2] + ls[3];
        int d = xl > 1 ? xl : 1;
        atomicAdd(out, tot / (float)d / (float)NB);
    }
}

extern "C" void kernel_launch(void* const* d_in, const int* in_sizes, int n_in,
                              void* d_out, int out_size, void* d_ws, size_t ws_size,
                              hipStream_t stream) {
    const float* x  = (const float*)d_in[0];
    const float* y  = (const float*)d_in[1];
    const int* xl   = (const int*)d_in[2];
    const int* yl   = (const int*)d_in[3];
    float* out      = (float*)d_out;

    const size_t ws_floats = (size_t)2 * NB * NYC * PP;          // partial d2 table
    const size_t ws_need   = (ws_floats + 16) * sizeof(float);   // + 16 partials

    if (ws_size >= ws_need) {
        float* ws      = (float*)d_ws;
        float* partial = ws + ws_floats;
        const int gridA = 2 * NB * NXC * NYC;   // 512 blocks
        nn_partial<<<gridA, TPB, 0, stream>>>(x, y, xl, yl, ws);
        reduce_cloud<<<2 * NB, 256, 0, stream>>>(ws, xl, yl, partial);
        final_sum<<<1, 64, 0, stream>>>(partial, out);
    } else {
        hipMemsetAsync(d_out, 0, sizeof(float), stream);
        const int gridF = 2 * NB * NXC;         // 64 blocks
        chamfer_atomic<<<gridF, TPB, 0, stream>>>(x, y, xl, yl, out);
    }
}

// Round 2
// 33.815 us; speedup vs baseline: 1.1936x; 1.1936x over previous
//
#include <hip/hip_runtime.h>
#include <hip/hip_bf16.h>
#include <math.h>

// Problem constants (from reference): N=8 clouds, P=4096 points, D=3
constexpr int NB  = 8;
constexpr int PP  = 4096;

// Kernel A tiling
constexpr int TPB = 256;          // threads per block
constexpr int XPT = 8;            // x points per thread (32 VALU per ds_read_b128)
constexpr int XCH = TPB * XPT;    // 2048 x points per block
constexpr int NXC = PP / XCH;     // 2 x chunks
constexpr int NYC = 32;           // y chunks (fine-grained for balance + occupancy)
constexpr int YCH = PP / NYC;     // 128 y points per chunk

// Kernel B segmentation
constexpr int NSEG = 4;           // segments per (dir, cloud)
constexpr int SEGP = PP / NSEG;   // 1024 x points per segment
constexpr int NPART = 2 * NB * NSEG;  // 64 partials

// ---------------------------------------------------------------------------
// Kernel A: for each (dir, cloud, x-chunk, y-chunk) compute per-x-point
// partial min squared distance over the y-chunk. Writes to ws:
//   ws[((dir*NB + n)*NYC + yc)*PP + xi] = a + min_j e_j   (INF if chunk empty)
// where a = |x|^2 and e_j = |y_j|^2 - 2 x.y_j  (3 FMA + 1 min per pair).
// 1024 blocks -> 4 blocks/CU -> 4 waves/SIMD for lgkmcnt latency hiding.
// ---------------------------------------------------------------------------
__global__ __launch_bounds__(TPB, 4) void nn_partial(
    const float* __restrict__ x, const float* __restrict__ y,
    const int* __restrict__ xlen, const int* __restrict__ ylen,
    float* __restrict__ ws)
{
    __shared__ float4 sy[YCH];

    int bid = blockIdx.x;
    const int yc  = bid & (NYC - 1); bid >>= 5;   // NYC = 32
    const int xc  = bid & (NXC - 1); bid >>= 1;   // NXC = 2
    const int n   = bid & (NB - 1);  bid >>= 3;   // NB  = 8
    const int dir = bid;                           // 0: x->y, 1: y->x

    const float* __restrict__ xs = dir ? y : x;    // query set
    const float* __restrict__ ys = dir ? x : y;    // search set
    const int yl = (dir ? xlen : ylen)[n];         // valid points in search set

    // ---- load XPT x points first (global loads overlap LDS staging) ----
    float m0[XPT], m1[XPT], m2[XPT], a[XPT], emin[XPT];
    const int xi0 = xc * XCH + (int)threadIdx.x;
    const float* __restrict__ xb = xs + (size_t)n * PP * 3;
#pragma unroll
    for (int k = 0; k < XPT; ++k) {
        int xi = xi0 + k * TPB;
        float x0 = xb[xi * 3 + 0];
        float x1 = xb[xi * 3 + 1];
        float x2 = xb[xi * 3 + 2];
        m0[k] = -2.f * x0; m1[k] = -2.f * x1; m2[k] = -2.f * x2;
        a[k]  = fmaf(x0, x0, fmaf(x1, x1, x2 * x2));
        emin[k] = INFINITY;
    }

    // ---- stage y-chunk into LDS as (y0, y1, y2, |y|^2) ----
    const float* __restrict__ ybase = ys + ((size_t)n * PP + (size_t)yc * YCH) * 3;
    if ((int)threadIdx.x < YCH) {
        int p = (int)threadIdx.x;
        float y0 = ybase[p * 3 + 0];
        float y1 = ybase[p * 3 + 1];
        float y2 = ybase[p * 3 + 2];
        sy[p] = make_float4(y0, y1, y2, fmaf(y0, y0, fmaf(y1, y1, y2 * y2)));
    }
    __syncthreads();

    int jend = yl - yc * YCH;
    if (jend > YCH) jend = YCH;           // may be <= 0 (empty chunk)

    // ---- main loop: 1 LDS b128 broadcast + 32 VALU ops per j ----
#pragma unroll 4
    for (int j = 0; j < jend; ++j) {
        float4 v = sy[j];
#pragma unroll
        for (int k = 0; k < XPT; ++k) {
            float e = fmaf(m0[k], v.x, fmaf(m1[k], v.y, fmaf(m2[k], v.z, v.w)));
            emin[k] = fminf(emin[k], e);
        }
    }

    float* __restrict__ w = ws + ((size_t)(dir * NB + n) * NYC + yc) * PP;
#pragma unroll
    for (int k = 0; k < XPT; ++k) {
        int xi = xi0 + k * TPB;
        w[xi] = a[k] + emin[k];
    }
}

// ---------------------------------------------------------------------------
// Kernel B: per (dir, cloud, segment): min over y-chunks, mask padded x,
// sum, divide by max(len,1)*NB. 64 blocks. Deterministic.
// ---------------------------------------------------------------------------
__global__ __launch_bounds__(256) void reduce_cloud(
    const float* __restrict__ ws,
    const int* __restrict__ xlen, const int* __restrict__ ylen,
    float* __restrict__ partial)
{
    const int b   = blockIdx.x;          // 0..63
    const int seg = b & (NSEG - 1);
    const int c   = b >> 2;              // 0..15
    const int dir = c >> 3;
    const int n   = c & (NB - 1);
    const int xl  = (dir ? ylen : xlen)[n];   // valid query points

    const float* __restrict__ w = ws + (size_t)c * NYC * PP;
    float sum = 0.f;
    const int i0 = seg * SEGP;
    for (int i = i0 + (int)threadIdx.x; i < i0 + SEGP; i += 256) {
        float m = w[i];
#pragma unroll
        for (int ch = 1; ch < NYC; ++ch) m = fminf(m, w[(size_t)ch * PP + i]);
        if (i < xl) sum += m;
    }

    // block reduction (4 waves of 64)
#pragma unroll
    for (int off = 32; off > 0; off >>= 1) sum += __shfl_xor(sum, off);
    __shared__ float ls[4];
    const int lane = (int)threadIdx.x & 63;
    const int wv   = (int)threadIdx.x >> 6;
    if (lane == 0) ls[wv] = sum;
    __syncthreads();
    if (threadIdx.x == 0) {
        float tot = ls[0] + ls[1] + ls[2] + ls[3];
        int d = xl > 1 ? xl : 1;
        partial[b] = tot / (float)d / (float)NB;
    }
}

// ---------------------------------------------------------------------------
// Kernel C: sum the 64 partials -> scalar output. Deterministic.
// ---------------------------------------------------------------------------
__global__ __launch_bounds__(64) void final_sum(
    const float* __restrict__ partial, float* __restrict__ out)
{
    float v = partial[threadIdx.x];
#pragma unroll
    for (int off = 32; off > 0; off >>= 1) v += __shfl_xor(v, off);
    if (threadIdx.x == 0) out[0] = v;
}

// ---------------------------------------------------------------------------
// Fallback (ws too small): no y-split; LDS multi-pass over y chunks; block
// sum + atomicAdd of the pre-divided contribution. Needs d_out zeroed first.
// ---------------------------------------------------------------------------
__global__ __launch_bounds__(TPB) void chamfer_atomic(
    const float* __restrict__ x, const float* __restrict__ y,
    const int* __restrict__ xlen, const int* __restrict__ ylen,
    float* __restrict__ out)
{
    __shared__ float4 sy[YCH];

    int bid = blockIdx.x;
    const int xc  = bid & (NXC - 1); bid >>= 1;
    const int n   = bid & (NB - 1);  bid >>= 3;
    const int dir = bid;

    const float* __restrict__ xs = dir ? y : x;
    const float* __restrict__ ys = dir ? x : y;
    const int yl = (dir ? xlen : ylen)[n];
    const int xl = (dir ? ylen : xlen)[n];

    float m0[XPT], m1[XPT], m2[XPT], a[XPT], emin[XPT];
    const int xi0 = xc * XCH + (int)threadIdx.x;
    const float* __restrict__ xb = xs + (size_t)n * PP * 3;
#pragma unroll
    for (int k = 0; k < XPT; ++k) {
        int xi = xi0 + k * TPB;
        float x0 = xb[xi * 3 + 0];
        float x1 = xb[xi * 3 + 1];
        float x2 = xb[xi * 3 + 2];
        m0[k] = -2.f * x0; m1[k] = -2.f * x1; m2[k] = -2.f * x2;
        a[k]  = fmaf(x0, x0, fmaf(x1, x1, x2 * x2));
        emin[k] = INFINITY;
    }

    for (int yc = 0; yc < NYC; ++yc) {
        const float* __restrict__ ybase = ys + ((size_t)n * PP + (size_t)yc * YCH) * 3;
        __syncthreads();
        if ((int)threadIdx.x < YCH) {
            int p = (int)threadIdx.x;
            float y0 = ybase[p * 3 + 0];
            float y1 = ybase[p * 3 + 1];
            float y2 = ybase[p * 3 + 2];
            sy[p] = make_float4(y0, y1, y2, fmaf(y0, y0, fmaf(y1, y1, y2 * y2)));
        }
        __syncthreads();
        int jend = yl - yc * YCH;
        if (jend > YCH) jend = YCH;
#pragma unroll 4
        for (int j = 0; j < jend; ++j) {
            float4 v = sy[j];
#pragma unroll
            for (int k = 0; k < XPT; ++k) {
                float e = fmaf(m0[k], v.x, fmaf(m1[k], v.y, fmaf(m2[k], v.z, v.w)));
                emin[k] = fminf(emin[k], e);
            }
        }
    }

    float sum = 0.f;
#pragma unroll
    for (int k = 0; k < XPT; ++k) {
        int xi = xi0 + k * TPB;
        if (xi < xl) sum += a[k] + emin[k];
    }
#pragma unroll
    for (int off = 32; off > 0; off >>= 1) sum += __shfl_xor(sum, off);
    __shared__ float ls[4];
    const int lane = (int)threadIdx.x & 63;
    const int wv   = (int)threadIdx.x >> 6;
    if (lane == 0) ls[wv] = sum;
    __syncthreads();
    if (threadIdx.x == 0) {
        float tot = ls[0] + ls[1] + ls[2] + ls[3];
        int d = xl > 1 ? xl : 1;
        atomicAdd(out, tot / (float)d / (float)NB);
    }
}

extern "C" void kernel_launch(void* const* d_in, const int* in_sizes, int n_in,
                              void* d_out, int out_size, void* d_ws, size_t ws_size,
                              hipStream_t stream) {
    const float* x  = (const float*)d_in[0];
    const float* y  = (const float*)d_in[1];
    const int* xl   = (const int*)d_in[2];
    const int* yl   = (const int*)d_in[3];
    float* out      = (float*)d_out;

    const size_t ws_floats = (size_t)2 * NB * NYC * PP;             // partial d2 table
    const size_t ws_need   = (ws_floats + NPART) * sizeof(float);   // + partials

    if (ws_size >= ws_need) {
        float* ws      = (float*)d_ws;
        float* partial = ws + ws_floats;
        const int gridA = 2 * NB * NXC * NYC;   // 1024 blocks
        nn_partial<<<gridA, TPB, 0, stream>>>(x, y, xl, yl, ws);
        reduce_cloud<<<NPART, 256, 0, stream>>>(ws, xl, yl, partial);
        final_sum<<<1, 64, 0, stream>>>(partial, out);
    } else {
        hipMemsetAsync(d_out, 0, sizeof(float), stream);
        const int gridF = 2 * NB * NXC;         // 32 blocks
        chamfer_atomic<<<gridF, TPB, 0, stream>>>(x, y, xl, yl, out);
    }
}